// Round 4
// baseline (3670.770 us; speedup 1.0000x reference)
//
#include <hip/hip_runtime.h>
#include <math.h>

// Problem constants
#define BATCH 4
#define SEQ   4096
#define DMODEL 1024
#define HEADS 16
#define HDIM  64
#define CHUNK 64
#define NCHUNK 64
#define NTOK  16384          // BATCH*SEQ
#define QKVC  3072           // 3*DMODEL
#define SCALE_F 0.35355339059327373f  // 64^-0.25

typedef unsigned short u16;

__device__ __forceinline__ float bf2f(u16 u) {
    return __uint_as_float(((unsigned)u) << 16);
}
__device__ __forceinline__ u16 f2bf(float f) {
    unsigned x = __float_as_uint(f);
    return (u16)((x + 0x7FFFu + ((x >> 16) & 1u)) >> 16);   // RNE
}

// typed 4-wide load/store helpers (fp32 or bf16 backing)
__device__ __forceinline__ float4 load4f(const float* p) { return *(const float4*)p; }
__device__ __forceinline__ float4 load4f(const u16* p) {
    ushort4 u = *(const ushort4*)p;
    return make_float4(bf2f(u.x), bf2f(u.y), bf2f(u.z), bf2f(u.w));
}
__device__ __forceinline__ void store4f(float* p, float4 v) { *(float4*)p = v; }
__device__ __forceinline__ void store4f(u16* p, float4 v) {
    ushort4 u;
    u.x = f2bf(v.x); u.y = f2bf(v.y); u.z = f2bf(v.z); u.w = f2bf(v.w);
    *(ushort4*)p = u;
}

// ---------------------------------------------------------------------------
// Tiled GEMM: C[M,N] = A[M,K] @ B[K,N]; tiles 64x64x16, 256 thr, 4x4 microtile
// AT/BT/CT each fp32 or bf16(u16); fp32 accumulate in registers.
// ---------------------------------------------------------------------------
template <typename AT, typename BT, typename CT>
__global__ __launch_bounds__(256)
void gemm_tiled(const AT* __restrict__ A, int lda,
                const BT* __restrict__ B, int ldb,
                CT* __restrict__ C, int ldc, int K)
{
    __shared__ float As[16][68];   // [k][row], padded
    __shared__ float Bs[16][64];   // [k][col]

    const int tid = threadIdx.x;
    const int tx = tid & 15, ty = tid >> 4;
    const int r0 = blockIdx.y * 64, c0 = blockIdx.x * 64;

    const int la_row = tid >> 2;         // 0..63
    const int la_col = (tid & 3) * 4;    // 0,4,8,12
    const int lb_row = tid >> 4;         // 0..15
    const int lb_col = (tid & 15) * 4;   // 0..60

    const AT* Aptr = A + (long)(r0 + la_row) * lda + la_col;
    const BT* Bptr = B + (long)lb_row * ldb + c0 + lb_col;

    float acc[4][4] = {};

    for (int k0 = 0; k0 < K; k0 += 16) {
        float4 a = load4f(Aptr + k0);
        float4 b = load4f(Bptr + (long)k0 * ldb);
        As[la_col + 0][la_row] = a.x;
        As[la_col + 1][la_row] = a.y;
        As[la_col + 2][la_row] = a.z;
        As[la_col + 3][la_row] = a.w;
        *(float4*)&Bs[lb_row][lb_col] = b;
        __syncthreads();
#pragma unroll
        for (int kk = 0; kk < 16; ++kk) {
            float4 av = *(const float4*)&As[kk][ty * 4];
            float4 bv = *(const float4*)&Bs[kk][tx * 4];
            acc[0][0] += av.x * bv.x; acc[0][1] += av.x * bv.y;
            acc[0][2] += av.x * bv.z; acc[0][3] += av.x * bv.w;
            acc[1][0] += av.y * bv.x; acc[1][1] += av.y * bv.y;
            acc[1][2] += av.y * bv.z; acc[1][3] += av.y * bv.w;
            acc[2][0] += av.z * bv.x; acc[2][1] += av.z * bv.y;
            acc[2][2] += av.z * bv.z; acc[2][3] += av.z * bv.w;
            acc[3][0] += av.w * bv.x; acc[3][1] += av.w * bv.y;
            acc[3][2] += av.w * bv.z; acc[3][3] += av.w * bv.w;
        }
        __syncthreads();
    }
#pragma unroll
    for (int i = 0; i < 4; ++i) {
        float4 o = make_float4(acc[i][0], acc[i][1], acc[i][2], acc[i][3]);
        store4f(&C[(long)(r0 + ty * 4 + i) * ldc + c0 + tx * 4], o);
    }
}

// ---------------------------------------------------------------------------
// RoPE + elu(x*scale)+1 applied in place to q and k slices (bf16 buffer).
// One thread per (b,n,w,h,d<32): handles (d, d+32).
// ---------------------------------------------------------------------------
__global__ __launch_bounds__(256)
void rope_elu_kernel(u16* __restrict__ qkv)
{
    int gid = blockIdx.x * 256 + threadIdx.x;   // 16,777,216 total
    int d = gid & 31;
    int h = (gid >> 5) & 15;
    int w = (gid >> 9) & 1;           // 0 = q, 1 = k
    int n = (gid >> 10) & 4095;
    int b = gid >> 22;

    long base = (long)(b * SEQ + n) * QKVC + w * DMODEL + h * HDIM + d;
    float x1 = bf2f(qkv[base]);
    float x2 = bf2f(qkv[base + 32]);

    float freq = (float)n * powf(10000.0f, -(float)d * (1.0f / 32.0f));
    float s, c;
    sincosf(freq, &s, &c);

    float y1 = (x1 * c - x2 * s) * SCALE_F;
    float y2 = (x1 * s + x2 * c) * SCALE_F;
    y1 = (y1 > 0.0f) ? (y1 + 1.0f) : __expf(y1);   // elu(x)+1
    y2 = (y2 > 0.0f) ? (y2 + 1.0f) : __expf(y2);
    qkv[base] = f2bf(y1);
    qkv[base + 32] = f2bf(y2);
}

// ---------------------------------------------------------------------------
// Linear-attention scan: one block per (b,h); iterates 64 chunks of 64 tokens
// sequentially, keeping KV[64][64] fp32 state + ksum[64] in LDS.
// Writes the attention output (bf16) in place over the q slice.
// ---------------------------------------------------------------------------
__global__ __launch_bounds__(256)
void attn_scan_kernel(u16* __restrict__ qkv)
{
    __shared__ u16 Qs[64][64];
    __shared__ u16 Ks[64][64];
    __shared__ u16 Vs[64][64];
    __shared__ float Sc[64][64];
    __shared__ float KV[64][64];
    __shared__ float kss[64];
    __shared__ float den[64];

    const int bh = blockIdx.x;
    const int b = bh >> 4, h = bh & 15;
    const int tid = threadIdx.x;
    const int t4 = tid >> 2, g = tid & 3;    // scores/out mapping
    const int m = tid & 63, dg = tid >> 6;   // update mapping

    for (int i = tid; i < 64 * 64; i += 256) ((float*)KV)[i] = 0.0f;
    if (tid < 64) kss[tid] = 0.0f;
    __syncthreads();

    for (int c = 0; c < NCHUNK; ++c) {
        const long base = (long)(b * SEQ + c * CHUNK) * QKVC + h * HDIM;

        // stage Q,K,V chunk (64x64 bf16 each)
#pragma unroll
        for (int j = 0; j < 4; ++j) {
            int i = (j * 256 + tid) * 4;
            int t = i >> 6, d = i & 63;
            const u16* src = qkv + base + (long)t * QKVC + d;
            *(ushort4*)&Qs[t][d] = *(const ushort4*)(src);
            *(ushort4*)&Ks[t][d] = *(const ushort4*)(src + DMODEL);
            *(ushort4*)&Vs[t][d] = *(const ushort4*)(src + 2 * DMODEL);
        }
        __syncthreads();

        // intra-chunk scores: Sc[t][s] = q_t . k_s  (s <= t), else 0
#pragma unroll
        for (int si = 0; si < 16; ++si) {
            int s = g * 16 + si;
            float a = 0.0f;
            if (s <= t4) {
#pragma unroll
                for (int d4 = 0; d4 < 16; ++d4) {
                    float4 qv = load4f(&Qs[t4][d4 * 4]);
                    float4 kv = load4f(&Ks[s][d4 * 4]);
                    a += qv.x * kv.x + qv.y * kv.y + qv.z * kv.z + qv.w * kv.w;
                }
            }
            Sc[t4][s] = a;
        }
        __syncthreads();

        // denominators (uses pre-update ksum state)
        if (tid < 64) {
            float dn = 0.0f;
            for (int d = 0; d < 64; ++d) dn += bf2f(Qs[tid][d]) * kss[d];
            for (int s = 0; s <= tid; ++s) dn += Sc[tid][s];
            den[tid] = 1.0f / fmaxf(dn, 1e-6f);
        }
        __syncthreads();

        // output: out[t][m] = q_t . KV[:,m] + sum_{s<=t} Sc[t][s] * V[s][m]
        float acc[16];
#pragma unroll
        for (int i = 0; i < 16; ++i) acc[i] = 0.0f;
        for (int d = 0; d < 64; ++d) {
            float qv = bf2f(Qs[t4][d]);
#pragma unroll
            for (int q4 = 0; q4 < 4; ++q4) {
                float4 kv = *(const float4*)&KV[d][g * 16 + q4 * 4];
                acc[q4 * 4 + 0] += qv * kv.x; acc[q4 * 4 + 1] += qv * kv.y;
                acc[q4 * 4 + 2] += qv * kv.z; acc[q4 * 4 + 3] += qv * kv.w;
            }
        }
        for (int s = 0; s <= t4; ++s) {
            float av = Sc[t4][s];
#pragma unroll
            for (int q4 = 0; q4 < 4; ++q4) {
                float4 vv = load4f(&Vs[s][g * 16 + q4 * 4]);
                acc[q4 * 4 + 0] += av * vv.x; acc[q4 * 4 + 1] += av * vv.y;
                acc[q4 * 4 + 2] += av * vv.z; acc[q4 * 4 + 3] += av * vv.w;
            }
        }
        {
            float r = den[t4];
            u16* dst = qkv + base + (long)t4 * QKVC + g * 16;
#pragma unroll
            for (int q4 = 0; q4 < 4; ++q4) {
                ushort4 o;
                o.x = f2bf(acc[q4 * 4 + 0] * r);
                o.y = f2bf(acc[q4 * 4 + 1] * r);
                o.z = f2bf(acc[q4 * 4 + 2] * r);
                o.w = f2bf(acc[q4 * 4 + 3] * r);
                *(ushort4*)(dst + q4 * 4) = o;
            }
        }
        __syncthreads();   // KV reads done before update writes

        // state update: KV[d][m] += sum_t K[t][d]*V[t][m]; ksum += sum_t k_t
        float upd[16];
#pragma unroll
        for (int i = 0; i < 16; ++i) upd[i] = 0.0f;
        for (int t = 0; t < 64; ++t) {
            float vv = bf2f(Vs[t][m]);
#pragma unroll
            for (int q4 = 0; q4 < 4; ++q4) {
                float4 kk = load4f(&Ks[t][dg * 16 + q4 * 4]);
                upd[q4 * 4 + 0] += kk.x * vv; upd[q4 * 4 + 1] += kk.y * vv;
                upd[q4 * 4 + 2] += kk.z * vv; upd[q4 * 4 + 3] += kk.w * vv;
            }
        }
#pragma unroll
        for (int i = 0; i < 16; ++i) KV[dg * 16 + i][m] += upd[i];
        if (tid < 64) {
            float s = 0.0f;
            for (int t = 0; t < 64; ++t) s += bf2f(Ks[t][tid]);
            kss[tid] += s;
        }
        __syncthreads();
    }
}

// ---------------------------------------------------------------------------
extern "C" void kernel_launch(void* const* d_in, const int* in_sizes, int n_in,
                              void* d_out, int out_size, void* d_ws, size_t ws_size,
                              hipStream_t stream)
{
    // Per the reference file: all inputs fp32, output fp32. The harness
    // compares in the bf16 DOMAIN (both sides cast), but storage is fp32.
    const float* x     = (const float*)d_in[0];
    const float* w_qkv = (const float*)d_in[1];
    const float* w_out = (const float*)d_in[2];
    float* out = (float*)d_out;
    u16* qkv = (u16*)d_ws;           // 16384 x 3072 bf16 = 100.7 MB workspace

    dim3 blk(256);

    // 1) qkv = x @ w_qkv  (M=16384, N=3072, K=1024), fp32 in, bf16 ws out
    gemm_tiled<float, float, u16><<<dim3(QKVC / 64, NTOK / 64), blk, 0, stream>>>(
        x, DMODEL, w_qkv, QKVC, qkv, QKVC, DMODEL);

    // 2) RoPE + elu+1 in place on q,k
    rope_elu_kernel<<<(BATCH * SEQ * 2 * HEADS * 32) / 256, blk, 0, stream>>>(qkv);

    // 3) linear-attention scan, one block per (b,h); out in place over q slice
    attn_scan_kernel<<<BATCH * HEADS, blk, 0, stream>>>(qkv);

    // 4) out = attn_out @ w_out  (A = q slice bf16, lda=3072), fp32 out
    gemm_tiled<u16, float, float><<<dim3(DMODEL / 64, NTOK / 64), blk, 0, stream>>>(
        qkv, QKVC, w_out, DMODEL, out, DMODEL, DMODEL);
}

// Round 5
// 690.869 us; speedup vs baseline: 5.3133x; 5.3133x over previous
//
#include <hip/hip_runtime.h>
#include <math.h>

// Problem constants
#define BATCH 4
#define SEQ   4096
#define DMODEL 1024
#define HEADS 16
#define HDIM  64
#define CHUNK 64
#define NCHUNK 64
#define NTOK  16384          // BATCH*SEQ
#define QKVC  3072           // 3*DMODEL
#define SCALE_F 0.35355339059327373f  // 64^-0.25

typedef unsigned short u16;
typedef _Float16 f16;
typedef __attribute__((ext_vector_type(8))) f16 f16x8;
typedef __attribute__((ext_vector_type(4))) float f32x4;

__device__ __forceinline__ u16 f2h(float f) { f16 h = (f16)f; return *(u16*)&h; }
__device__ __forceinline__ float h2f(u16 u) { f16 h = *(f16*)&u; return (float)h; }
__device__ __forceinline__ float4 load4h(const u16* p) {
    ushort4 u = *(const ushort4*)p;
    return make_float4(h2f(u.x), h2f(u.y), h2f(u.z), h2f(u.w));
}
__device__ __forceinline__ void storeC(u16* p, float v) { *p = f2h(v); }
__device__ __forceinline__ void storeC(float* p, float v) { *p = v; }

// ---------------------------------------------------------------------------
// fp32 -> fp16 flat convert (n multiple of 1024)
// ---------------------------------------------------------------------------
__global__ __launch_bounds__(256)
void convert_f32_f16(const float* __restrict__ src, u16* __restrict__ dst)
{
    long i = ((long)blockIdx.x * 256 + threadIdx.x) * 4;
    float4 v = *(const float4*)(src + i);
    ushort4 o; o.x = f2h(v.x); o.y = f2h(v.y); o.z = f2h(v.z); o.w = f2h(v.w);
    *(ushort4*)(dst + i) = o;
}

// ---------------------------------------------------------------------------
// Transpose + convert: src fp32 [R][C] -> dst fp16 [C][R], dst row stride dld.
// 64x64 tiles, grid (C/64, R/64).
// ---------------------------------------------------------------------------
__global__ __launch_bounds__(256)
void transpose_convert(const float* __restrict__ src, int C,
                       u16* __restrict__ dst, int dld)
{
    __shared__ u16 tile[64][72];
    const int r0 = blockIdx.y * 64, c0 = blockIdx.x * 64;
    const int t = threadIdx.x;
    const int rr = t >> 4, cc4 = (t & 15) * 4;
#pragma unroll
    for (int j = 0; j < 4; ++j) {
        int r = rr + j * 16;
        float4 v = *(const float4*)(src + (long)(r0 + r) * C + c0 + cc4);
        tile[cc4 + 0][r] = f2h(v.x);
        tile[cc4 + 1][r] = f2h(v.y);
        tile[cc4 + 2][r] = f2h(v.z);
        tile[cc4 + 3][r] = f2h(v.w);
    }
    __syncthreads();
#pragma unroll
    for (int j = 0; j < 4; ++j) {
        int c = rr + j * 16;                       // output row (source col)
        ushort4 o = *(ushort4*)&tile[c][cc4];
        *(ushort4*)(dst + (long)(c0 + c) * dld + r0 + cc4) = o;
    }
}

// ---------------------------------------------------------------------------
// MFMA fp16 GEMM: C[M,N] = A[M,K] @ B[K,N], B given TRANSPOSED (BT[N][K]).
// 128x128 tile, BK=32, 256 thr = 4 waves (2x2 of 64x64), 4x4 mfma 16x16x32.
// ---------------------------------------------------------------------------
template <typename CT>
__global__ __launch_bounds__(256)
void gemm_mfma(const u16* __restrict__ A, int lda,
               const u16* __restrict__ BT, int ldbt,
               CT* __restrict__ C, int ldc, int K)
{
    __shared__ u16 As[128][40];   // [m][k], 80B rows
    __shared__ u16 Bs[128][40];   // [n][k]

    const int tid = threadIdx.x;
    const long m0 = blockIdx.y * 128, n0 = blockIdx.x * 128;
    const int w = tid >> 6, lane = tid & 63;
    const int wm = (w >> 1) * 64, wn = (w & 1) * 64;
    const int fr = lane & 15;            // frag row (m or n)
    const int fk = (lane >> 4) * 8;      // frag k offset (quad*8)
    const int srow = tid >> 3, sk = (tid & 7) * 4;   // staging map

    f32x4 acc[4][4];
#pragma unroll
    for (int i = 0; i < 4; ++i)
#pragma unroll
        for (int j = 0; j < 4; ++j)
#pragma unroll
            for (int r = 0; r < 4; ++r) acc[i][j][r] = 0.0f;

    for (int kt = 0; kt < K; kt += 32) {
#pragma unroll
        for (int it = 0; it < 4; ++it) {
            int r = srow + it * 32;
            *(ushort4*)&As[r][sk] = *(const ushort4*)(A + (m0 + r) * (long)lda + kt + sk);
            *(ushort4*)&Bs[r][sk] = *(const ushort4*)(BT + (n0 + r) * (long)ldbt + kt + sk);
        }
        __syncthreads();
        f16x8 af[4], bf[4];
#pragma unroll
        for (int i = 0; i < 4; ++i) {
            af[i] = *(const f16x8*)&As[wm + i * 16 + fr][fk];
            bf[i] = *(const f16x8*)&Bs[wn + i * 16 + fr][fk];
        }
#pragma unroll
        for (int i = 0; i < 4; ++i)
#pragma unroll
            for (int j = 0; j < 4; ++j)
                acc[i][j] = __builtin_amdgcn_mfma_f32_16x16x32_f16(af[i], bf[j], acc[i][j], 0, 0, 0);
        __syncthreads();
    }

    // C/D: col = lane&15, row = (lane>>4)*4 + reg
    const long cm = m0 + wm + (lane >> 4) * 4;
    const long cn = n0 + wn + fr;
#pragma unroll
    for (int i = 0; i < 4; ++i)
#pragma unroll
        for (int j = 0; j < 4; ++j)
#pragma unroll
            for (int r = 0; r < 4; ++r)
                storeC(&C[(cm + i * 16 + r) * ldc + cn + j * 16], acc[i][j][r]);
}

// ---------------------------------------------------------------------------
// RoPE + elu(x*scale)+1 in place on q,k slices (fp16 qkv buffer).
// ---------------------------------------------------------------------------
__global__ __launch_bounds__(256)
void rope_elu_kernel(u16* __restrict__ qkv)
{
    int gid = blockIdx.x * 256 + threadIdx.x;   // 16,777,216 total
    int d = gid & 31;
    int h = (gid >> 5) & 15;
    int w = (gid >> 9) & 1;           // 0 = q, 1 = k
    int n = (gid >> 10) & 4095;
    int b = gid >> 22;

    long base = (long)(b * SEQ + n) * QKVC + w * DMODEL + h * HDIM + d;
    float x1 = h2f(qkv[base]);
    float x2 = h2f(qkv[base + 32]);

    float freq = (float)n * powf(10000.0f, -(float)d * (1.0f / 32.0f));
    float s, c;
    sincosf(freq, &s, &c);

    float y1 = (x1 * c - x2 * s) * SCALE_F;
    float y2 = (x1 * s + x2 * c) * SCALE_F;
    y1 = (y1 > 0.0f) ? (y1 + 1.0f) : __expf(y1);   // elu(x)+1
    y2 = (y2 > 0.0f) ? (y2 + 1.0f) : __expf(y2);
    qkv[base] = f2h(y1);
    qkv[base + 32] = f2h(y2);
}

// ---------------------------------------------------------------------------
// Per-(b,h,chunk): S[d][m] = sum_t k_t[d] v_t[m] (fp16), ksum[d] (fp32)
// ---------------------------------------------------------------------------
__global__ __launch_bounds__(256)
void chunk_sums_kernel(const u16* __restrict__ qkv,
                       u16* __restrict__ S, float* __restrict__ ksum)
{
    __shared__ u16 Ks[64][64];
    __shared__ u16 Vs[64][64];

    const int blk = blockIdx.x;
    const int c = blk & 63, bh = blk >> 6;
    const int b = bh >> 4, h = bh & 15;
    const int tid = threadIdx.x;

    const long base = (long)(b * SEQ + c * CHUNK) * QKVC + h * HDIM;
#pragma unroll
    for (int j = 0; j < 4; ++j) {
        int i4 = (j * 256 + tid) * 4;
        int t = i4 >> 6, d = i4 & 63;
        const u16* src = qkv + base + (long)t * QKVC + d;
        *(ushort4*)&Ks[t][d] = *(const ushort4*)(src + DMODEL);
        *(ushort4*)&Vs[t][d] = *(const ushort4*)(src + 2 * DMODEL);
    }
    __syncthreads();

    const int m = tid & 63, dg = tid >> 6;
    float acc[16];
#pragma unroll
    for (int i = 0; i < 16; ++i) acc[i] = 0.0f;
    for (int t = 0; t < 64; ++t) {
        float vv = h2f(Vs[t][m]);
#pragma unroll
        for (int q = 0; q < 4; ++q) {
            float4 kk = load4h(&Ks[t][dg * 16 + q * 4]);
            acc[q * 4 + 0] += kk.x * vv; acc[q * 4 + 1] += kk.y * vv;
            acc[q * 4 + 2] += kk.z * vv; acc[q * 4 + 3] += kk.w * vv;
        }
    }
    const long sb = (long)blk * 4096;
#pragma unroll
    for (int i = 0; i < 16; ++i)
        S[sb + (dg * 16 + i) * 64 + m] = f2h(acc[i]);

    if (tid < 64) {
        float s = 0.0f;
        for (int t = 0; t < 64; ++t) s += h2f(Ks[t][tid]);
        ksum[(long)blk * 64 + tid] = s;
    }
}

// ---------------------------------------------------------------------------
// Exclusive prefix scan over chunks (per bh): S (fp16) and ksum (fp32).
// grid = 64 bh x 16 slices.
// ---------------------------------------------------------------------------
__global__ __launch_bounds__(256)
void scan_kernel(u16* __restrict__ S, float* __restrict__ ksum)
{
    const int blk = blockIdx.x;
    const int slice = blk & 15, bh = blk >> 4;
    const int p = slice * 256 + threadIdx.x;
    const long base = (long)bh * NCHUNK * 4096 + p;
    float acc = 0.0f;
    for (int c = 0; c < NCHUNK; ++c) {
        long idx = base + (long)c * 4096;
        float tmp = h2f(S[idx]);
        S[idx] = f2h(acc);
        acc += tmp;
    }
    if (slice == 0 && threadIdx.x < 64) {
        const long kb = (long)bh * NCHUNK * 64 + threadIdx.x;
        float ka = 0.0f;
        for (int c = 0; c < NCHUNK; ++c) {
            float t = ksum[kb + (long)c * 64];
            ksum[kb + (long)c * 64] = ka;
            ka += t;
        }
    }
}

// ---------------------------------------------------------------------------
// Per-(b,h,chunk) output: out = (causal QK^T)V + Q@KV_prefix, / denom.
// In place over the q slice. Mirrors the validated sequential kernel.
// ---------------------------------------------------------------------------
__global__ __launch_bounds__(256)
void chunk_out_kernel(u16* __restrict__ qkv,
                      const u16* __restrict__ S, const float* __restrict__ ksum)
{
    __shared__ u16 Qs[64][64];
    __shared__ u16 Ks[64][64];
    __shared__ u16 Vs[64][64];
    __shared__ float Sc[64][64];
    __shared__ float KV[64][64];
    __shared__ float kss[64];
    __shared__ float den[64];

    const int blk = blockIdx.x;
    const int c = blk & 63, bh = blk >> 6;
    const int b = bh >> 4, h = bh & 15;
    const int tid = threadIdx.x;
    const int t4 = tid >> 2, g = tid & 3;

    const long base = (long)(b * SEQ + c * CHUNK) * QKVC + h * HDIM;
#pragma unroll
    for (int j = 0; j < 4; ++j) {
        int i4 = (j * 256 + tid) * 4;
        int t = i4 >> 6, d = i4 & 63;
        const u16* src = qkv + base + (long)t * QKVC + d;
        *(ushort4*)&Qs[t][d] = *(const ushort4*)(src);
        *(ushort4*)&Ks[t][d] = *(const ushort4*)(src + DMODEL);
        *(ushort4*)&Vs[t][d] = *(const ushort4*)(src + 2 * DMODEL);
        *(float4*)&((float*)KV)[i4] = load4h(S + (long)blk * 4096 + i4);
    }
    if (tid < 64) kss[tid] = ksum[(long)blk * 64 + tid];
    __syncthreads();

    // intra-chunk scores
#pragma unroll
    for (int si = 0; si < 16; ++si) {
        int s = g * 16 + si;
        float a = 0.0f;
        if (s <= t4) {
#pragma unroll
            for (int d4 = 0; d4 < 16; ++d4) {
                float4 qv = load4h(&Qs[t4][d4 * 4]);
                float4 kv = load4h(&Ks[s][d4 * 4]);
                a += qv.x * kv.x + qv.y * kv.y + qv.z * kv.z + qv.w * kv.w;
            }
        }
        Sc[t4][s] = a;
    }
    __syncthreads();

    // denominators (prefix ksum + intra part)
    if (tid < 64) {
        float dn = 0.0f;
        for (int d = 0; d < 64; ++d) dn += h2f(Qs[tid][d]) * kss[d];
        for (int s = 0; s <= tid; ++s) dn += Sc[tid][s];
        den[tid] = 1.0f / fmaxf(dn, 1e-6f);
    }
    __syncthreads();

    // outputs
    float acc[16];
#pragma unroll
    for (int i = 0; i < 16; ++i) acc[i] = 0.0f;
    for (int d = 0; d < 64; ++d) {
        float qv = h2f(Qs[t4][d]);
#pragma unroll
        for (int q = 0; q < 4; ++q) {
            float4 kv = *(const float4*)&KV[d][g * 16 + q * 4];
            acc[q * 4 + 0] += qv * kv.x; acc[q * 4 + 1] += qv * kv.y;
            acc[q * 4 + 2] += qv * kv.z; acc[q * 4 + 3] += qv * kv.w;
        }
    }
    for (int s = 0; s <= t4; ++s) {
        float av = Sc[t4][s];
#pragma unroll
        for (int q = 0; q < 4; ++q) {
            float4 vv = load4h(&Vs[s][g * 16 + q * 4]);
            acc[q * 4 + 0] += av * vv.x; acc[q * 4 + 1] += av * vv.y;
            acc[q * 4 + 2] += av * vv.z; acc[q * 4 + 3] += av * vv.w;
        }
    }
    float r = den[t4];
    u16* dst = qkv + base + (long)t4 * QKVC + g * 16;
#pragma unroll
    for (int q = 0; q < 4; ++q) {
        ushort4 o;
        o.x = f2h(acc[q * 4 + 0] * r); o.y = f2h(acc[q * 4 + 1] * r);
        o.z = f2h(acc[q * 4 + 2] * r); o.w = f2h(acc[q * 4 + 3] * r);
        *(ushort4*)(dst + q * 4) = o;
    }
}

// ---------------------------------------------------------------------------
extern "C" void kernel_launch(void* const* d_in, const int* in_sizes, int n_in,
                              void* d_out, int out_size, void* d_ws, size_t ws_size,
                              hipStream_t stream)
{
    const float* x     = (const float*)d_in[0];
    const float* w_qkv = (const float*)d_in[1];
    const float* w_out = (const float*)d_in[2];
    float* out = (float*)d_out;

    // Workspace: qkv fp16 only (100.7 MB — proven-safe footprint).
    u16* qkv = (u16*)d_ws;
    // d_out doubles as scratch before the final GEMM writes it:
    //   [0 .. 33.5MB)  x_f16   (GEMM1 A)      -- later aliased by S (chunk states)
    //   [33.5 .. 39.8) wqkvT   (GEMM1 B)      -- later aliased by ksum
    u16* xf16  = (u16*)d_out;                         // 16384*1024 fp16
    u16* wqkvT = xf16 + (size_t)NTOK * DMODEL;        // 3072*1024 fp16
    u16* S     = (u16*)d_out;                         // 64*64*4096 fp16 (alias xf16)
    float* ksum = (float*)((char*)d_out + 33554432);  // 64*64*64 fp32 (alias wqkvT)
    // w_outT lives in the dead k-slice of qkv (rows 0..1023, cols 1024..2047)
    u16* woutT = qkv + 1024;                          // [n][k] with row stride 3072

    dim3 blk(256);

    // 0) conversions for GEMM1
    convert_f32_f16<<<NTOK * DMODEL / 1024, blk, 0, stream>>>(x, xf16);
    transpose_convert<<<dim3(QKVC / 64, DMODEL / 64), blk, 0, stream>>>(
        w_qkv, QKVC, wqkvT, DMODEL);

    // 1) qkv = x @ w_qkv  (MFMA fp16)
    gemm_mfma<u16><<<dim3(QKVC / 128, NTOK / 128), blk, 0, stream>>>(
        xf16, DMODEL, wqkvT, DMODEL, qkv, QKVC, DMODEL);

    // 2) RoPE + elu+1 in place on q,k
    rope_elu_kernel<<<(BATCH * SEQ * 2 * HEADS * 32) / 256, blk, 0, stream>>>(qkv);

    // 3) chunk-parallel linear attention
    chunk_sums_kernel<<<64 * NCHUNK, blk, 0, stream>>>(qkv, S, ksum);
    scan_kernel<<<64 * 16, blk, 0, stream>>>(S, ksum);
    chunk_out_kernel<<<64 * NCHUNK, blk, 0, stream>>>(qkv, S, ksum);

    // 4) w_out transpose into dead k-slice, then out = attn @ w_out (MFMA)
    transpose_convert<<<dim3(DMODEL / 64, DMODEL / 64), blk, 0, stream>>>(
        w_out, DMODEL, woutT, QKVC);
    gemm_mfma<float><<<dim3(DMODEL / 128, NTOK / 128), blk, 0, stream>>>(
        qkv, QKVC, woutT, QKVC, out, DMODEL, DMODEL);
}

// Round 6
// 444.408 us; speedup vs baseline: 8.2599x; 1.5546x over previous
//
#include <hip/hip_runtime.h>
#include <math.h>

// Problem constants
#define BATCH 4
#define SEQ   4096
#define DMODEL 1024
#define HEADS 16
#define HDIM  64
#define CHUNK 64
#define NCHUNK 64
#define NTOK  16384          // BATCH*SEQ
#define QKVC  3072           // 3*DMODEL
#define SCALE_F 0.35355339059327373f  // 64^-0.25
#define ROPE_K 0.4152410118609203f    // log2(10000)/32

typedef unsigned short u16;
typedef _Float16 f16;
typedef __attribute__((ext_vector_type(8))) f16 f16x8;
typedef __attribute__((ext_vector_type(4))) float f32x4;

__device__ __forceinline__ u16 f2h(float f) { f16 h = (f16)f; return *(u16*)&h; }
__device__ __forceinline__ float h2f(u16 u) { f16 h = *(f16*)&u; return (float)h; }
__device__ __forceinline__ void storeC(u16* p, float v) { *p = f2h(v); }
__device__ __forceinline__ void storeC(float* p, float v) { *p = v; }

// ---------------------------------------------------------------------------
// fp32 -> fp16 flat convert (n multiple of 1024)
// ---------------------------------------------------------------------------
__global__ __launch_bounds__(256)
void convert_f32_f16(const float* __restrict__ src, u16* __restrict__ dst)
{
    long i = ((long)blockIdx.x * 256 + threadIdx.x) * 4;
    float4 v = *(const float4*)(src + i);
    ushort4 o; o.x = f2h(v.x); o.y = f2h(v.y); o.z = f2h(v.z); o.w = f2h(v.w);
    *(ushort4*)(dst + i) = o;
}

// ---------------------------------------------------------------------------
// Transpose + convert: src fp32 [R][C] -> dst fp16 [C][R], dst row stride dld.
// ---------------------------------------------------------------------------
__global__ __launch_bounds__(256)
void transpose_convert(const float* __restrict__ src, int C,
                       u16* __restrict__ dst, int dld)
{
    __shared__ u16 tile[64][72];
    const int r0 = blockIdx.y * 64, c0 = blockIdx.x * 64;
    const int t = threadIdx.x;
    const int rr = t >> 4, cc4 = (t & 15) * 4;
#pragma unroll
    for (int j = 0; j < 4; ++j) {
        int r = rr + j * 16;
        float4 v = *(const float4*)(src + (long)(r0 + r) * C + c0 + cc4);
        tile[cc4 + 0][r] = f2h(v.x);
        tile[cc4 + 1][r] = f2h(v.y);
        tile[cc4 + 2][r] = f2h(v.z);
        tile[cc4 + 3][r] = f2h(v.w);
    }
    __syncthreads();
#pragma unroll
    for (int j = 0; j < 4; ++j) {
        int c = rr + j * 16;
        ushort4 o = *(ushort4*)&tile[c][cc4];
        *(ushort4*)(dst + (long)(c0 + c) * dld + r0 + cc4) = o;
    }
}

// ---------------------------------------------------------------------------
// MFMA fp16 GEMM: C[M,N] = A[M,K] @ B[K,N], B given TRANSPOSED (BT[N][K]).
// 128x128 tile, BK=32, 4 waves (2x2 of 64x64), 4x4 mfma 16x16x32.
// ROPE=true: fused RoPE + elu(x*SCALE)+1 epilogue on cols < 2048 (q,k).
// ---------------------------------------------------------------------------
template <typename CT, bool ROPE>
__global__ __launch_bounds__(256)
void gemm_mfma(const u16* __restrict__ A, int lda,
               const u16* __restrict__ BT, int ldbt,
               CT* __restrict__ C, int ldc, int K)
{
    __shared__ u16 As[128][40];   // [m][k], 80B rows (16B-aligned)
    __shared__ u16 Bs[128][40];   // [n][k]

    const int tid = threadIdx.x;
    const long m0 = blockIdx.y * 128, n0 = blockIdx.x * 128;
    const int w = tid >> 6, lane = tid & 63;
    const int wm = (w >> 1) * 64, wn = (w & 1) * 64;
    const int fr = lane & 15;            // frag row (m or n)
    const int fk = (lane >> 4) * 8;      // frag k offset (quad*8)
    const int srow = tid >> 3, sk = (tid & 7) * 4;   // staging map

    f32x4 acc[4][4];
#pragma unroll
    for (int i = 0; i < 4; ++i)
#pragma unroll
        for (int j = 0; j < 4; ++j)
#pragma unroll
            for (int r = 0; r < 4; ++r) acc[i][j][r] = 0.0f;

    for (int kt = 0; kt < K; kt += 32) {
#pragma unroll
        for (int it = 0; it < 4; ++it) {
            int r = srow + it * 32;
            *(ushort4*)&As[r][sk] = *(const ushort4*)(A + (m0 + r) * (long)lda + kt + sk);
            *(ushort4*)&Bs[r][sk] = *(const ushort4*)(BT + (n0 + r) * (long)ldbt + kt + sk);
        }
        __syncthreads();
        f16x8 af[4], bf[4];
#pragma unroll
        for (int i = 0; i < 4; ++i) {
            af[i] = *(const f16x8*)&As[wm + i * 16 + fr][fk];
            bf[i] = *(const f16x8*)&Bs[wn + i * 16 + fr][fk];
        }
#pragma unroll
        for (int i = 0; i < 4; ++i)
#pragma unroll
            for (int j = 0; j < 4; ++j)
                acc[i][j] = __builtin_amdgcn_mfma_f32_16x16x32_f16(af[i], bf[j], acc[i][j], 0, 0, 0);
        __syncthreads();
    }

    // C/D: col = lane&15 (+16j), row = quad*4 + reg (+16i)
    const long cm = m0 + wm + (lane >> 4) * 4;
    const long cn = n0 + wn + fr;

    if (ROPE && cn < 2048) {
        // lane's 4 cols within its 64-aligned head: fr, fr+16, fr+32, fr+48.
        // rope pairs: (j0,j2) with d2=fr; (j1,j3) with d2=fr+16.
        const float invf0 = exp2f(-(float)fr * ROPE_K);
        const float invf1 = exp2f(-(float)(fr + 16) * ROPE_K);
#pragma unroll
        for (int i = 0; i < 4; ++i)
#pragma unroll
            for (int r = 0; r < 4; ++r) {
                long row = cm + i * 16 + r;
                float n = (float)(int)(row & (SEQ - 1));
                float s0, c0, s1, c1;
                __sincosf(n * invf0, &s0, &c0);
                __sincosf(n * invf1, &s1, &c1);
                float x1 = acc[i][0][r], x2 = acc[i][2][r];
                float x3 = acc[i][1][r], x4 = acc[i][3][r];
                float u1 = (x1 * c0 - x2 * s0) * SCALE_F;
                float u2 = (x1 * s0 + x2 * c0) * SCALE_F;
                float u3 = (x3 * c1 - x4 * s1) * SCALE_F;
                float u4 = (x3 * s1 + x4 * c1) * SCALE_F;
                u1 = (u1 > 0.0f) ? (u1 + 1.0f) : __expf(u1);
                u2 = (u2 > 0.0f) ? (u2 + 1.0f) : __expf(u2);
                u3 = (u3 > 0.0f) ? (u3 + 1.0f) : __expf(u3);
                u4 = (u4 > 0.0f) ? (u4 + 1.0f) : __expf(u4);
                CT* pr = C + row * ldc + cn;
                storeC(pr, u1); storeC(pr + 16, u3);
                storeC(pr + 32, u2); storeC(pr + 48, u4);
            }
    } else {
#pragma unroll
        for (int i = 0; i < 4; ++i)
#pragma unroll
            for (int j = 0; j < 4; ++j)
#pragma unroll
                for (int r = 0; r < 4; ++r)
                    storeC(&C[(cm + i * 16 + r) * ldc + cn + j * 16], acc[i][j][r]);
    }
}

// ---------------------------------------------------------------------------
// Per-(b,h,chunk): S[m][d] = sum_t V[t][m] K[t][d]  (= (K^T V)^T, fp16),
// ksum[d] = sum_t K[t][d] (fp32). MFMA 16x16x32.
// ---------------------------------------------------------------------------
__global__ __launch_bounds__(256)
void chunk_sums_mfma(const u16* __restrict__ qkv,
                     u16* __restrict__ S, float* __restrict__ ksum)
{
    __shared__ u16 Kt[64][72];   // [d][t]
    __shared__ u16 Vt[64][72];   // [m][t]

    const int blk = blockIdx.x;
    const int c = blk & 63, bh = blk >> 6;
    const int b = bh >> 4, h = bh & 15;
    const int tid = threadIdx.x;
    const long base = (long)(b * SEQ + c * CHUNK) * QKVC + h * HDIM;

#pragma unroll
    for (int j = 0; j < 4; ++j) {
        int i4 = (j * 256 + tid) * 4;
        int t = i4 >> 6, d = i4 & 63;
        const u16* src = qkv + base + (long)t * QKVC + d;
        ushort4 kk = *(const ushort4*)(src + DMODEL);
        ushort4 vv = *(const ushort4*)(src + 2 * DMODEL);
        Kt[d + 0][t] = kk.x; Kt[d + 1][t] = kk.y;
        Kt[d + 2][t] = kk.z; Kt[d + 3][t] = kk.w;
        Vt[d + 0][t] = vv.x; Vt[d + 1][t] = vv.y;
        Vt[d + 2][t] = vv.z; Vt[d + 3][t] = vv.w;
    }
    __syncthreads();

    const int w = tid >> 6, lane = tid & 63;
    const int fr = lane & 15, quad = lane >> 4;

    // D[m][d] = sum_t Vt[m][t] * K[t][d];  A = Vt, B-op layout [d][t] = Kt
    f16x8 af0 = *(const f16x8*)&Vt[w * 16 + fr][quad * 8];
    f16x8 af1 = *(const f16x8*)&Vt[w * 16 + fr][32 + quad * 8];
    f32x4 acc[4];
#pragma unroll
    for (int j = 0; j < 4; ++j)
#pragma unroll
        for (int r = 0; r < 4; ++r) acc[j][r] = 0.0f;
#pragma unroll
    for (int j = 0; j < 4; ++j) {
        f16x8 b0 = *(const f16x8*)&Kt[j * 16 + fr][quad * 8];
        f16x8 b1 = *(const f16x8*)&Kt[j * 16 + fr][32 + quad * 8];
        acc[j] = __builtin_amdgcn_mfma_f32_16x16x32_f16(af0, b0, acc[j], 0, 0, 0);
        acc[j] = __builtin_amdgcn_mfma_f32_16x16x32_f16(af1, b1, acc[j], 0, 0, 0);
    }
    const long sb = (long)blk * 4096;
    const int mrow = w * 16 + quad * 4;
#pragma unroll
    for (int j = 0; j < 4; ++j)
#pragma unroll
        for (int r = 0; r < 4; ++r)
            S[sb + (mrow + r) * 64 + j * 16 + fr] = f2h(acc[j][r]);

    if (tid < 64) {
        float s = 0.0f;
        for (int t = 0; t < 64; ++t) s += h2f(Kt[tid][t]);
        ksum[(long)blk * 64 + tid] = s;
    }
}

// ---------------------------------------------------------------------------
// Exclusive prefix scan over chunks (per bh): S (fp16) and ksum (fp32).
// ---------------------------------------------------------------------------
__global__ __launch_bounds__(256)
void scan_kernel(u16* __restrict__ S, float* __restrict__ ksum)
{
    const int blk = blockIdx.x;
    const int slice = blk & 15, bh = blk >> 4;
    const int p = slice * 256 + threadIdx.x;
    const long base = (long)bh * NCHUNK * 4096 + p;
    float acc = 0.0f;
    for (int c = 0; c < NCHUNK; ++c) {
        long idx = base + (long)c * 4096;
        float tmp = h2f(S[idx]);
        S[idx] = f2h(acc);
        acc += tmp;
    }
    if (slice == 0 && threadIdx.x < 64) {
        const long kb = (long)bh * NCHUNK * 64 + threadIdx.x;
        float ka = 0.0f;
        for (int c = 0; c < NCHUNK; ++c) {
            float t = ksum[kb + (long)c * 64];
            ksum[kb + (long)c * 64] = ka;
            ka += t;
        }
    }
}

// ---------------------------------------------------------------------------
// Per-(b,h,chunk) output via MFMA:
//   Sc = causal(Q K^T); out = Sc @ V + Q @ KV_prefix; out /= denom.
// In place over the q slice. S holds KV^T prefix ([m][d]).
// ---------------------------------------------------------------------------
__global__ __launch_bounds__(256)
void chunk_out_mfma(u16* __restrict__ qkv,
                    const u16* __restrict__ S, const float* __restrict__ ksum)
{
    __shared__ u16 Qs[64][72];    // [t][d]
    __shared__ u16 Ks[64][72];    // [s][d]  (B-op for QK^T)
    __shared__ u16 Vt[64][72];    // [m][s]  (B-op for Sc@V)
    __shared__ u16 KVt[64][72];   // [m][d]  (B-op for Q@KV)
    __shared__ u16 Sch[64][72];   // [t][s]  masked scores (A-op for Sc@V)
    __shared__ float kss[64];
    __shared__ float den[64];

    const int blk = blockIdx.x;
    const int c = blk & 63, bh = blk >> 6;
    const int b = bh >> 4, h = bh & 15;
    const int tid = threadIdx.x;
    const long base = (long)(b * SEQ + c * CHUNK) * QKVC + h * HDIM;

#pragma unroll
    for (int j = 0; j < 4; ++j) {
        int i4 = (j * 256 + tid) * 4;
        int t = i4 >> 6, d = i4 & 63;
        const u16* src = qkv + base + (long)t * QKVC + d;
        *(ushort4*)&Qs[t][d] = *(const ushort4*)(src);
        *(ushort4*)&Ks[t][d] = *(const ushort4*)(src + DMODEL);
        ushort4 vv = *(const ushort4*)(src + 2 * DMODEL);
        Vt[d + 0][t] = vv.x; Vt[d + 1][t] = vv.y;
        Vt[d + 2][t] = vv.z; Vt[d + 3][t] = vv.w;
        *(ushort4*)&KVt[t][d] = *(const ushort4*)(S + (long)blk * 4096 + i4);
    }
    if (tid < 64) kss[tid] = ksum[(long)blk * 64 + tid];
    __syncthreads();

    const int w = tid >> 6, lane = tid & 63;
    const int fr = lane & 15, quad = lane >> 4;
    const int trow = w * 16 + quad * 4;   // C-layout row base

    // --- Sc = Q K^T (wave w: rows w*16..+16) ---
    f16x8 aq0 = *(const f16x8*)&Qs[w * 16 + fr][quad * 8];
    f16x8 aq1 = *(const f16x8*)&Qs[w * 16 + fr][32 + quad * 8];
    f32x4 sc[4];
#pragma unroll
    for (int j = 0; j < 4; ++j)
#pragma unroll
        for (int r = 0; r < 4; ++r) sc[j][r] = 0.0f;
#pragma unroll
    for (int j = 0; j < 4; ++j) {
        f16x8 b0 = *(const f16x8*)&Ks[j * 16 + fr][quad * 8];
        f16x8 b1 = *(const f16x8*)&Ks[j * 16 + fr][32 + quad * 8];
        sc[j] = __builtin_amdgcn_mfma_f32_16x16x32_f16(aq0, b0, sc[j], 0, 0, 0);
        sc[j] = __builtin_amdgcn_mfma_f32_16x16x32_f16(aq1, b1, sc[j], 0, 0, 0);
    }
    // causal mask + store fp16
#pragma unroll
    for (int j = 0; j < 4; ++j)
#pragma unroll
        for (int r = 0; r < 4; ++r) {
            int t = trow + r, s = j * 16 + fr;
            Sch[t][s] = f2h(s <= t ? sc[j][r] : 0.0f);
        }
    __syncthreads();

    // --- denominators ---
    if (tid < 64) {
        float dn = 0.0f;
        for (int d = 0; d < 64; ++d) dn += h2f(Qs[tid][d]) * kss[d];
        for (int s = 0; s <= tid; ++s) dn += h2f(Sch[tid][s]);
        den[tid] = 1.0f / fmaxf(dn, 1e-6f);
    }
    __syncthreads();

    // --- out = Sch @ V + Q @ KV ---
    f16x8 as0 = *(const f16x8*)&Sch[w * 16 + fr][quad * 8];
    f16x8 as1 = *(const f16x8*)&Sch[w * 16 + fr][32 + quad * 8];
    f32x4 oc[4];
#pragma unroll
    for (int j = 0; j < 4; ++j)
#pragma unroll
        for (int r = 0; r < 4; ++r) oc[j][r] = 0.0f;
#pragma unroll
    for (int j = 0; j < 4; ++j) {
        f16x8 b0 = *(const f16x8*)&Vt[j * 16 + fr][quad * 8];
        f16x8 b1 = *(const f16x8*)&Vt[j * 16 + fr][32 + quad * 8];
        oc[j] = __builtin_amdgcn_mfma_f32_16x16x32_f16(as0, b0, oc[j], 0, 0, 0);
        oc[j] = __builtin_amdgcn_mfma_f32_16x16x32_f16(as1, b1, oc[j], 0, 0, 0);
        f16x8 k0 = *(const f16x8*)&KVt[j * 16 + fr][quad * 8];
        f16x8 k1 = *(const f16x8*)&KVt[j * 16 + fr][32 + quad * 8];
        oc[j] = __builtin_amdgcn_mfma_f32_16x16x32_f16(aq0, k0, oc[j], 0, 0, 0);
        oc[j] = __builtin_amdgcn_mfma_f32_16x16x32_f16(aq1, k1, oc[j], 0, 0, 0);
    }
    // scale by 1/denom, store in place over q slice
#pragma unroll
    for (int j = 0; j < 4; ++j)
#pragma unroll
        for (int r = 0; r < 4; ++r) {
            int t = trow + r;
            qkv[base + (long)t * QKVC + j * 16 + fr] = f2h(oc[j][r] * den[t]);
        }
}

// ---------------------------------------------------------------------------
extern "C" void kernel_launch(void* const* d_in, const int* in_sizes, int n_in,
                              void* d_out, int out_size, void* d_ws, size_t ws_size,
                              hipStream_t stream)
{
    const float* x     = (const float*)d_in[0];
    const float* w_qkv = (const float*)d_in[1];
    const float* w_out = (const float*)d_in[2];
    float* out = (float*)d_out;

    // Workspace: qkv fp16 only (100.7 MB — proven-safe footprint).
    u16* qkv = (u16*)d_ws;
    // d_out doubles as scratch before the final GEMM writes it:
    u16* xf16  = (u16*)d_out;                         // 16384*1024 fp16
    u16* wqkvT = xf16 + (size_t)NTOK * DMODEL;        // 3072*1024 fp16
    u16* S     = (u16*)d_out;                         // 64*64*4096 fp16 (alias xf16)
    float* ksum = (float*)((char*)d_out + 33554432);  // 64*64*64 fp32 (alias wqkvT)
    // w_outT lives in the dead k-slice of qkv (rows 0..1023, cols 1024..2047)
    u16* woutT = qkv + 1024;                          // [n][k], row stride 3072

    dim3 blk(256);

    // 0) conversions for GEMM1
    convert_f32_f16<<<NTOK * DMODEL / 1024, blk, 0, stream>>>(x, xf16);
    transpose_convert<<<dim3(QKVC / 64, DMODEL / 64), blk, 0, stream>>>(
        w_qkv, QKVC, wqkvT, DMODEL);

    // 1) qkv = x @ w_qkv with fused RoPE+elu on q,k cols (MFMA fp16)
    gemm_mfma<u16, true><<<dim3(QKVC / 128, NTOK / 128), blk, 0, stream>>>(
        xf16, DMODEL, wqkvT, DMODEL, qkv, QKVC, DMODEL);

    // 2) chunk-parallel linear attention (all MFMA)
    chunk_sums_mfma<<<64 * NCHUNK, blk, 0, stream>>>(qkv, S, ksum);
    scan_kernel<<<64 * 16, blk, 0, stream>>>(S, ksum);
    chunk_out_mfma<<<64 * NCHUNK, blk, 0, stream>>>(qkv, S, ksum);

    // 3) w_out transpose into dead k-slice, then out = attn @ w_out (MFMA)
    transpose_convert<<<dim3(DMODEL / 64, DMODEL / 64), blk, 0, stream>>>(
        w_out, DMODEL, woutT, QKVC);
    gemm_mfma<float, false><<<dim3(DMODEL / 128, NTOK / 128), blk, 0, stream>>>(
        qkv, QKVC, woutT, QKVC, out, DMODEL, DMODEL);
}